// Round 10
// baseline (187.132 us; speedup 1.0000x reference)
//
#include <hip/hip_runtime.h>
#include <hip/hip_bf16.h>

// Problem constants: B=64, Cin=3, H=W=64, O=16, k=7, fh=fw=58
#define O_ 16
#define CIN 3
#define NBUCK 1024
#define WB 0.01171875f          // bucket width = 12/1024, range [-6, 6)
#define SCALE 85.33333333f      // 1/WB
#define NCLASS 169              // 13 row-classes x 13 col-classes

// output geometry
#define SEG 10092u              // fh*fh*Cin
#define OSEG 161472u            // O*SEG
#define OUT1 10334208u          // B*OSEG
#define NOUT 31002624u          // 3*OUT1

// scratch in the TAIL of d_out (fill overwrites it last). float offsets:
#define TAIL_BASE (NOUT - 786432u)     // 30,216,192
#define T_BHIST 0u                      // 3*169*1024 = 519,168 count hist (global atomics)
#define HIST_V4 129792u                 // 519168/4

typedef float v4f __attribute__((ext_vector_type(4)));

// ---------------------------------------------------------------------------
// 0) zero: parallel clear of the hist region + gsum banks (~2 MB, ~1.5 us).
// ---------------------------------------------------------------------------
__global__ __launch_bounds__(256) void zero_kernel(
    float* __restrict__ tail, float* __restrict__ gsum)
{
    v4f z = {0.f, 0.f, 0.f, 0.f};
    v4f* dst = (v4f*)(tail + T_BHIST);
    unsigned stride = gridDim.x * blockDim.x;
    for (unsigned i = blockIdx.x * blockDim.x + threadIdx.x; i < HIST_V4; i += stride)
        dst[i] = z;
    if (blockIdx.x == 0 && threadIdx.x < 64) gsum[threadIdx.x] = 0.f;
}

// ---------------------------------------------------------------------------
// 1) build: branch-free histogramming. 384 blocks (half plane each).
//    Per pixel: class calc (~8 VALU) + ONE spread global atomicAdd.
//    No LDS, no scalars, no flush loops -- R9's build stalled on 52-deep
//    same-address LDS atomics at 4-waves/CU occupancy.
//    Full range +-6 w/ 1024 buckets: snap error ~1e2 absolute vs 5e5 thresh.
// ---------------------------------------------------------------------------
__global__ __launch_bounds__(256) void build_kernel(
    const float* __restrict__ x, float* __restrict__ tail)
{
    const int plane = blockIdx.x >> 1;          // 0..191
    const int half  = blockIdx.x & 1;
    const int c     = plane % 3;
    const float4* src = (const float4*)(x + plane * 4096);
    float* hist = tail + T_BHIST + (unsigned)c * (NCLASS * NBUCK);

#pragma unroll
    for (int it = 0; it < 2; ++it) {
        int f4 = half * 512 + it * 256 + threadIdx.x;
        float4 val = src[f4];
        float vv[4] = {val.x, val.y, val.z, val.w};
        int pix0 = f4 * 4;
#pragma unroll
        for (int e = 0; e < 4; ++e) {
            int idx = pix0 + e;
            int py = idx >> 6, px = idx & 63;
            int rc = (py < 6) ? py : ((py >= 58) ? py - 51 : 6);
            int cc = (px < 6) ? px : ((px >= 58) ? px - 51 : 6);
            int b = min(max((int)fmaf(vv[e], SCALE, 512.0f), 0), NBUCK - 1);
            atomicAdd(&hist[((rc * 13 + cc) << 10) + b], 1.f);
        }
    }
}

// ---------------------------------------------------------------------------
// 2) query: fused scan + query. Block per (channel, 8-class chunk) = 66.
//    Prologue: each wave scans 2 class-hists (1024 buckets) into T tables
//    held in LDS (T[j] = T0 + WB*(2Q[j] - j*N), double shuffle prefix scan)
//    -- this absorbs R9's tbuild kernel and its global table round trip.
//    Main: thread=(hm,o,ts); accA += lerp(T,k) over valid taps; accL from
//    analytic N and hist-derived S. Block-reduce -> 64 atomics into gsum.
// ---------------------------------------------------------------------------
#define QCHUNK 8
#define NCHUNK 22               // ceil(169/8)

__global__ __launch_bounds__(256) void query_kernel(
    const float* __restrict__ Kh, const float* __restrict__ Km,
    const float* __restrict__ tail, float* __restrict__ gsum)
{
    __shared__ float sT[QCHUNK][NBUCK + 1];   // 32.8 KB, odd stride
    __shared__ float sS[QCHUNK];
    __shared__ float sK[2][16][49];
    __shared__ float sredA[32][8];
    __shared__ float sredL[32][8];

    const int c     = blockIdx.x / NCHUNK;
    const int chunk = blockIdx.x % NCHUNK;
    const int cl0   = chunk * QCHUNK;
    const int ncl   = min(QCHUNK, NCLASS - cl0);

    const int lane = threadIdx.x & 63;
    const int wid  = threadIdx.x >> 6;

    // ---- phase A: scan 2 tables per wave ----
    for (int l = wid; l < ncl; l += 4) {
        const float* hrow = tail + T_BHIST + (unsigned)(c * NCLASS + cl0 + l) * NBUCK;
        float carry = 0.f, t0acc = 0.f;
#pragma unroll
        for (int ch = 0; ch < 16; ++ch) {
            int b = ch * 64 + lane;
            float cnt = hrow[b];
            t0acc += (float)b * cnt;
            float ic = cnt;
#pragma unroll
            for (int off = 1; off < 64; off <<= 1) {
                float tc = __shfl_up(ic, off);
                if (lane >= off) ic += tc;
            }
            sT[l][b] = carry + ic;            // inclusive prefix P[b]
            carry += __shfl(ic, 63);
        }
        const float N = carry;
#pragma unroll
        for (int off = 32; off > 0; off >>= 1) t0acc += __shfl_down(t0acc, off);
        const float t0tot = __shfl(t0acc, 0);
        const float T0 = WB * t0tot;

        float carryQ = 0.f;
#pragma unroll
        for (int ch = 0; ch < 16; ++ch) {
            int b = ch * 64 + lane;
            float pv = sT[l][b];
            float ic = pv;
#pragma unroll
            for (int off = 1; off < 64; off <<= 1) {
                float tc = __shfl_up(ic, off);
                if (lane >= off) ic += tc;
            }
            float Q = carryQ + ic - pv;       // exclusive prefix of P
            sT[l][b] = T0 + WB * (2.f * Q - (float)b * N);
            carryQ += __shfl(ic, 63);
        }
        if (lane == 0) {
            sT[l][NBUCK] = T0 + WB * (2.f * carryQ - (float)NBUCK * N);
            sS[l] = -6.0f * N + WB * (t0tot + 0.5f * N);   // sum of snapped values
        }
    }
    for (int i = threadIdx.x; i < 2 * 16 * 49; i += 256) {
        int hm = i / 784, r = i - hm * 784, o = r / 49, t = r - o * 49;
        sK[hm][o][t] = (hm ? Km : Kh)[o * 147 + c * 49 + t];
    }
    __syncthreads();

    // ---- phase B: queries ----
    const int hm = threadIdx.x >> 7;
    const int o  = (threadIdx.x >> 3) & 15;
    const int ts = threadIdx.x & 7;

    float accA = 0.f, accL = 0.f;
    for (int l = 0; l < ncl; ++l) {
        int cl = cl0 + l;
        int rc = cl / 13, cc = cl - rc * 13;
        int dyl = max(0, rc - 6), dyh = min(6, rc);
        int dxl = max(0, cc - 6), dxh = min(6, cc);
        float nr  = (rc == 6) ? 52.f : 1.f;
        float nc_ = (cc == 6) ? 52.f : 1.f;
        float Ncl = nr * nc_ * 64.f;
        float Scl = sS[l];
        for (int t = ts; t < 49; t += 8) {
            int dy = t / 7, dx = t - dy * 7;
            if (dy >= dyl && dy <= dyh && dx >= dxl && dx <= dxh) {
                float k = sK[hm][o][t];
                float fb = fmaf(k, SCALE, 511.5f);          // (k - center_0)/WB
                int j = min(max((int)fb, 0), NBUCK - 1);
                float frac = fb - (float)j;
                float t0 = sT[l][j], t1 = sT[l][j + 1];
                accA += t0 + frac * (t1 - t0);
                accL += k * Ncl - Scl;
            }
        }
    }
    sredA[hm * 16 + o][ts] = accA;
    sredL[hm * 16 + o][ts] = accL;
    __syncthreads();
    if (threadIdx.x < 64) {
        int idx  = threadIdx.x >> 1;
        int part = threadIdx.x & 1;
        const float (*sr)[8] = part ? sredL : sredA;
        float s = 0.f;
#pragma unroll
        for (int q = 0; q < 8; ++q) s += sr[idx][q];
        atomicAdd(&gsum[part * 32 + idx], s);
    }
}

// ---------------------------------------------------------------------------
// 3) fill: fold A/L banks -> s_hit/s_miss; broadcast-fill 124 MB (roofline).
//    s_hit = -0.5*(accL_h + accA_h);  s_miss = 0.5*(accA_m - accL_m)
// ---------------------------------------------------------------------------
__global__ __launch_bounds__(256) void fill_kernel(
    const float* __restrict__ gsum, v4f* __restrict__ out, unsigned n4)
{
    __shared__ float sv[48];
    if (threadIdx.x < 48) {
        int o = threadIdx.x & 15, grp = threadIdx.x >> 4;
        float h = -0.5f * (gsum[32 + o] + gsum[o]);
        float m =  0.5f * (gsum[16 + o] - gsum[48 + o]);
        sv[threadIdx.x] = (grp == 0) ? (h - m) : ((grp == 1) ? h : m);
    }
    __syncthreads();
    unsigned stride = gridDim.x * blockDim.x;
    for (unsigned i = blockIdx.x * blockDim.x + threadIdx.x; i < n4; i += stride) {
        unsigned f = i * 4u;
        unsigned w   = f / OUT1;
        unsigned rem = f - w * OUT1;
        unsigned o   = (rem % OSEG) / SEG;
        float val = sv[w * 16 + o];
        v4f pk = {val, val, val, val};
        __builtin_nontemporal_store(pk, &out[i]);
    }
}

extern "C" void kernel_launch(void* const* d_in, const int* in_sizes, int n_in,
                              void* d_out, int out_size, void* d_ws, size_t ws_size,
                              hipStream_t stream)
{
    const float* x  = (const float*)d_in[0];
    const float* Kh = (const float*)d_in[1];
    const float* Km = (const float*)d_in[2];
    float* out  = (float*)d_out;
    float* tail = out + TAIL_BASE;
    float* gsum = (float*)d_ws;    // 64 floats: [0..32) A-bank, [32..64) L-bank

    zero_kernel <<<256, 256, 0, stream>>>(tail, gsum);
    build_kernel<<<384, 256, 0, stream>>>(x, tail);
    query_kernel<<<3 * NCHUNK, 256, 0, stream>>>(Kh, Km, tail, gsum);
    fill_kernel <<<4096, 256, 0, stream>>>(gsum, (v4f*)out, NOUT / 4u);
}

// Round 11
// 83.829 us; speedup vs baseline: 2.2323x; 2.2323x over previous
//
#include <hip/hip_runtime.h>
#include <hip/hip_bf16.h>

// Problem constants: B=64, Cin=3, H=W=64, O=16, k=7, fh=fw=58
#define NBUCK 1024
#define WB 0.01171875f          // bucket width = 12/1024, range [-6, 6)
#define SCALE 85.33333333f      // 1/WB

// output geometry
#define SEG 10092u              // fh*fh*Cin
#define OSEG 161472u            // O*SEG
#define OUT1 10334208u          // B*OSEG
#define NOUT 31002624u          // 3*OUT1

// scratch in the TAIL of d_out (fill overwrites it last). float offsets:
#define TAIL_BASE (NOUT - 2097152u)    // 28,905,472
#define P_PART 0u                       // [48][25][1024] private hist copies (plain stores)
#define P_PACK 1228800u                 // [3][144][64] exact corner pixel values
#define P_TTAB 1256448u                 // [75][1025] T tables
#define P_STAB 1333323u                 // [75] S per table

typedef float v4f __attribute__((ext_vector_type(4)));

// ---------------------------------------------------------------------------
// 1) build: 48 blocks x 1024 thr; block = (channel, 4-batch group).
//    25 LDS histograms (F + 12 rows + 12 cols), spread-bucket LDS atomics
//    (Gaussian -> ~2-way bank alias, free). Corner pixels ALSO stored exactly
//    to P_PACK. Flush = plain coalesced stores to a private slot.
//    NO global atomics anywhere (R10's 133us lesson).
// ---------------------------------------------------------------------------
__global__ __launch_bounds__(1024) void build_kernel(
    const float* __restrict__ x, float* __restrict__ tail)
{
    __shared__ float sH[25 * 1024];     // 100 KB
    const int c = blockIdx.x >> 4;      // 0..2
    const int g = blockIdx.x & 15;      // 0..15
    for (int i = threadIdx.x; i < 25 * 1024; i += 1024) sH[i] = 0.f;
    __syncthreads();

#pragma unroll
    for (int pb = 0; pb < 4; ++pb) {
        const int batch = g * 4 + pb;
        const int plane = batch * 3 + c;
        float4 val = ((const float4*)x)[plane * 1024 + threadIdx.x];
        float vv[4] = {val.x, val.y, val.z, val.w};
        const int pix0 = threadIdx.x * 4;
#pragma unroll
        for (int e = 0; e < 4; ++e) {
            int idx = pix0 + e;
            int py = idx >> 6, px = idx & 63;
            float v = vv[e];
            int b = min(max((int)fmaf(v, SCALE, 512.f), 0), NBUCK - 1);
            atomicAdd(&sH[b], 1.f);                              // F
            bool rb = (py < 6) | (py >= 58);
            bool cb = (px < 6) | (px >= 58);
            int ri = (py < 6) ? py : py - 52;                    // 0..11
            int ci = (px < 6) ? px : px - 52;                    // 0..11
            if (rb) atomicAdd(&sH[(1 + ri) * 1024 + b], 1.f);    // row tables
            if (cb) atomicAdd(&sH[(13 + ci) * 1024 + b], 1.f);   // col tables
            if (rb & cb)
                tail[P_PACK + ((unsigned)c * 144 + ri * 12 + ci) * 64u + batch] = v;
        }
    }
    __syncthreads();
    float* dst = tail + P_PART + (unsigned)blockIdx.x * 25600u;
    for (int i = threadIdx.x; i < 25600; i += 1024) dst[i] = sH[i];
}

// ---------------------------------------------------------------------------
// 2) scan: 75 blocks x 64 (one wave per (c, table)). Sum the 16 private
//    copies, then double shuffle-prefix-scan -> T[1025] + S. Block 0 also
//    zeros gsum (runs before query in-stream).
//    T[j] = T0 + WB*(2Q[j] - j*N), T0 = WB*(sum b*cnt + N/2), S = T0 - 6N.
// ---------------------------------------------------------------------------
__global__ __launch_bounds__(64) void scan_kernel(
    float* __restrict__ tail, float* __restrict__ gsum)
{
    __shared__ float P[NBUCK];
    const int tab = blockIdx.x;                  // c*25 + tid
    const int c = tab / 25, tid = tab - c * 25;
    const int lane = threadIdx.x;
    if (blockIdx.x == 0) gsum[lane] = 0.f;       // 64 floats

    float carry = 0.f, t0acc = 0.f;
#pragma unroll 4
    for (int ch = 0; ch < 16; ++ch) {
        int b = ch * 64 + lane;
        float cnt = 0.f;
#pragma unroll
        for (int gg = 0; gg < 16; ++gg)
            cnt += tail[P_PART + (unsigned)(c * 16 + gg) * 25600u + tid * 1024u + b];
        t0acc += (float)b * cnt;
        float ic = cnt;
#pragma unroll
        for (int off = 1; off < 64; off <<= 1) {
            float t = __shfl_up(ic, off);
            if (lane >= off) ic += t;
        }
        P[b] = carry + ic;
        carry += __shfl(ic, 63);
    }
    const float N = carry;
#pragma unroll
    for (int off = 32; off > 0; off >>= 1) t0acc += __shfl_down(t0acc, off);
    const float t0tot = __shfl(t0acc, 0);
    const float T0 = WB * (t0tot + 0.5f * N);

    float* T = tail + P_TTAB + (unsigned)tab * 1025u;
    float carryQ = 0.f;
#pragma unroll 4
    for (int ch = 0; ch < 16; ++ch) {
        int b = ch * 64 + lane;
        float pv = P[b];
        float ic = pv;
#pragma unroll
        for (int off = 1; off < 64; off <<= 1) {
            float t = __shfl_up(ic, off);
            if (lane >= off) ic += t;
        }
        float Q = carryQ + ic - pv;              // exclusive prefix of P
        T[b] = T0 + WB * (2.f * Q - (float)b * N);
        carryQ += __shfl(ic, 63);
    }
    if (lane == 0) {
        T[NBUCK] = T0 + WB * (2.f * carryQ - (float)NBUCK * N);
        tail[P_STAB + tab] = T0 - 6.f * N;       // S = sum of snapped values
    }
}

// ---------------------------------------------------------------------------
// 3) query: 147 blocks = (c, tap). Inclusion-exclusion:
//      abs = T_F(k) - sum_6 T_rowinv(k) - sum_6 T_colinv(k) + exact corners
//      lin = k*212992 - (S_F - sum S_inv)  + exact corner (k - v)
//    Invalid row ids for dy: q<dy ? q : 6+q  (q=0..5); same for cols/dx.
//    13 tables staged to LDS (53 KB); 2304 corner values staged (9 KB),
//    read bank-conflict-free (slice-interleaved). 32 queries x 8 slices.
// ---------------------------------------------------------------------------
__global__ __launch_bounds__(256) void query_kernel(
    const float* __restrict__ Kh, const float* __restrict__ Km,
    const float* __restrict__ tail, float* __restrict__ gsum)
{
    __shared__ float sT[13][1025];
    __shared__ float sC[2304];
    __shared__ float sS13[13];
    __shared__ float sredA[32][8];
    __shared__ float sredL[32][8];

    const int c  = blockIdx.x / 49;
    const int t  = blockIdx.x - c * 49;
    const int dy = t / 7, dx = t - dy * 7;

    for (int i = threadIdx.x; i < 13 * 1025; i += 256) {
        int s = i / 1025, j = i - s * 1025;
        int tb;
        if (s == 0) tb = 0;
        else if (s < 7)  { int q = s - 1; tb = 1 + ((q < dy) ? q : 6 + q); }
        else             { int q = s - 7; tb = 13 + ((q < dx) ? q : 6 + q); }
        sT[s][j] = tail[P_TTAB + (unsigned)(c * 25 + tb) * 1025u + j];
    }
    if (threadIdx.x < 13) {
        int s = threadIdx.x, tb;
        if (s == 0) tb = 0;
        else if (s < 7)  { int q = s - 1; tb = 1 + ((q < dy) ? q : 6 + q); }
        else             { int q = s - 7; tb = 13 + ((q < dx) ? q : 6 + q); }
        sS13[s] = tail[P_STAB + c * 25 + tb];
    }
    for (int i = threadIdx.x; i < 2304; i += 256) {
        int cell = i >> 6, batch = i & 63;
        int qr = cell / 6, qc = cell - qr * 6;
        int ri = (qr < dy) ? qr : 6 + qr;
        int ci = (qc < dx) ? qc : 6 + qc;
        sC[i] = tail[P_PACK + ((unsigned)c * 144 + ri * 12 + ci) * 64u + batch];
    }
    __syncthreads();

    const int q  = threadIdx.x >> 3;   // 0..31 = hm*16+o
    const int sl = threadIdx.x & 7;
    const int hm = q >> 4, o = q & 15;
    const float k = (hm ? Km : Kh)[o * 147 + c * 49 + t];

    float accA = 0.f, accL = 0.f;
    // exact corners, slice-interleaved (stride 8 -> 8 distinct banks, q-broadcast)
    for (int step = 0; step < 288; ++step) {
        float v = sC[sl + 8 * step];
        accA += fabsf(k - v);
        accL += k - v;
    }
    if (sl == 0) {
        float fb = fmaf(k, SCALE, 512.f);
        int j = min(max((int)fb, 0), NBUCK - 1);
        float fr = fb - (float)j;
        float A = sT[0][j] + fr * (sT[0][j + 1] - sT[0][j]);
        float Sm = sS13[0];
#pragma unroll
        for (int s = 1; s < 13; ++s) {
            A  -= sT[s][j] + fr * (sT[s][j + 1] - sT[s][j]);
            Sm -= sS13[s];
        }
        accA += A;
        accL += k * 212992.f - Sm;     // 212992 = 262144 - 2*6*4096
    }
    sredA[q][sl] = accA;
    sredL[q][sl] = accL;
    __syncthreads();
    if (threadIdx.x < 64) {
        int idx  = threadIdx.x >> 1;
        int part = threadIdx.x & 1;
        const float (*sr)[8] = part ? sredL : sredA;
        float s = 0.f;
#pragma unroll
        for (int qq = 0; qq < 8; ++qq) s += sr[idx][qq];
        atomicAdd(&gsum[part * 32 + idx], s);
    }
}

// ---------------------------------------------------------------------------
// 4) fill: fold A/L banks -> s_hit/s_miss; broadcast-fill 124 MB (roofline).
// ---------------------------------------------------------------------------
__global__ __launch_bounds__(256) void fill_kernel(
    const float* __restrict__ gsum, v4f* __restrict__ out, unsigned n4)
{
    __shared__ float sv[48];
    if (threadIdx.x < 48) {
        int o = threadIdx.x & 15, grp = threadIdx.x >> 4;
        float h = -0.5f * (gsum[32 + o] + gsum[o]);
        float m =  0.5f * (gsum[16 + o] - gsum[48 + o]);
        sv[threadIdx.x] = (grp == 0) ? (h - m) : ((grp == 1) ? h : m);
    }
    __syncthreads();
    unsigned stride = gridDim.x * blockDim.x;
    for (unsigned i = blockIdx.x * blockDim.x + threadIdx.x; i < n4; i += stride) {
        unsigned f = i * 4u;
        unsigned w   = f / OUT1;
        unsigned rem = f - w * OUT1;
        unsigned o   = (rem % OSEG) / SEG;
        float val = sv[w * 16 + o];
        v4f pk = {val, val, val, val};
        __builtin_nontemporal_store(pk, &out[i]);
    }
}

extern "C" void kernel_launch(void* const* d_in, const int* in_sizes, int n_in,
                              void* d_out, int out_size, void* d_ws, size_t ws_size,
                              hipStream_t stream)
{
    const float* x  = (const float*)d_in[0];
    const float* Kh = (const float*)d_in[1];
    const float* Km = (const float*)d_in[2];
    float* out  = (float*)d_out;
    float* tail = out + TAIL_BASE;
    float* gsum = (float*)d_ws;    // 64 floats: [0..32) A-bank, [32..64) L-bank

    build_kernel<<<48, 1024, 0, stream>>>(x, tail);
    scan_kernel <<<75, 64, 0, stream>>>(tail, gsum);
    query_kernel<<<147, 256, 0, stream>>>(Kh, Km, tail, gsum);
    fill_kernel <<<4096, 256, 0, stream>>>(gsum, (v4f*)out, NOUT / 4u);
}

// Round 13
// 72.435 us; speedup vs baseline: 2.5835x; 1.1573x over previous
//
#include <hip/hip_runtime.h>
#include <hip/hip_bf16.h>

// Problem constants: B=64, Cin=3, H=W=64, O=16, k=7, fh=fw=58
#define NBUCK 2048
#define WB 0.005859375f         // bucket width = 12/2048, range [-6, 6)
#define SCALE 170.6666667f      // 1/WB

// output geometry
#define SEG 10092u              // fh*fh*Cin
#define OSEG 161472u            // O*SEG
#define OUT1 10334208u          // B*OSEG
#define NOUT 31002624u          // 3*OUT1

// scratch in the TAIL of d_out (fill overwrites it last). float offsets:
// table slots per channel: [0..16)=F-parts(4 planes each), [16..28)=rows, [28..40)=cols
#define TAIL_BASE (NOUT - 524288u)     // 30,478,336
#define P_TTAB 0u                       // [120][2049] T tables = 245,880
#define P_STAB 245880u                  // [120] S per table
#define P_PACK 246000u                  // [3][144][64] exact corner pixels = 27,648

typedef float v4f __attribute__((ext_vector_type(4)));

// ---------------------------------------------------------------------------
// 1) build: 120 independent blocks (c*40 + slot). Each block: own 2048-bucket
//    LDS hist -> in-LDS wave0 double-prefix-scan -> own T[2049]+S to global.
//    No cross-block reduction anywhere (R10/R11 lesson: serial small-grid
//    stages with per-CU BW/latency limits were the hidden 30-50us).
//    F-part blocks (4 planes, 64KB read) also store exact corner pixels.
// ---------------------------------------------------------------------------
__global__ __launch_bounds__(1024) void build_kernel(
    const float* __restrict__ x, float* __restrict__ tail, float* __restrict__ gsum)
{
    __shared__ float sH[NBUCK];         // 8 KB
    const int blk = blockIdx.x;         // == table index, 0..119
    const int c   = blk / 40;
    const int t40 = blk - c * 40;
    for (int i = threadIdx.x; i < NBUCK; i += 1024) sH[i] = 0.f;
    if (blk == 0 && threadIdx.x < 64) gsum[threadIdx.x] = 0.f;
    __syncthreads();

    if (t40 < 16) {
        // F-part: planes 4g..4g+3 of channel c (+ corner pack)
        const int g = t40;
        for (int pb = 0; pb < 4; ++pb) {
            const int batch = g * 4 + pb;
            const int plane = batch * 3 + c;
            float4 val = ((const float4*)x)[plane * 1024 + threadIdx.x];
            float vv[4] = {val.x, val.y, val.z, val.w};
            const int pix0 = threadIdx.x * 4;
#pragma unroll
            for (int e = 0; e < 4; ++e) {
                const int idx = pix0 + e;
                const int py = idx >> 6, px = idx & 63;
                const float v = vv[e];
                const int b = min(max((int)fmaf(v, SCALE, 1024.f), 0), NBUCK - 1);
                atomicAdd(&sH[b], 1.f);
                const bool rb = (py < 6) | (py >= 58);
                const bool cb = (px < 6) | (px >= 58);
                if (rb & cb) {
                    const int ri = (py < 6) ? py : py - 52;
                    const int ci = (px < 6) ? px : px - 52;
                    tail[P_PACK + ((unsigned)c * 144 + ri * 12 + ci) * 64u + batch] = v;
                }
            }
        }
    } else if (t40 < 28) {
        // row table ri: row py over all 64 planes of channel c (4096 px)
        const int ri = t40 - 16;
        const int py = (ri < 6) ? ri : ri + 52;
        const int b_ = threadIdx.x >> 4, q = threadIdx.x & 15;
        float4 val = ((const float4*)x)[(b_ * 3 + c) * 1024 + py * 16 + q];
        float vv[4] = {val.x, val.y, val.z, val.w};
#pragma unroll
        for (int e = 0; e < 4; ++e) {
            const int b = min(max((int)fmaf(vv[e], SCALE, 1024.f), 0), NBUCK - 1);
            atomicAdd(&sH[b], 1.f);
        }
    } else {
        // col table ci: column px over all rows/planes of channel c (4096 px)
        const int ci = t40 - 28;
        const int px = (ci < 6) ? ci : ci + 52;
        const int b_ = threadIdx.x >> 4, py0 = (threadIdx.x & 15) * 4;
        const float* base = x + (b_ * 3 + c) * 4096 + px;
#pragma unroll
        for (int e = 0; e < 4; ++e) {
            const float v = base[(py0 + e) * 64];
            const int b = min(max((int)fmaf(v, SCALE, 1024.f), 0), NBUCK - 1);
            atomicAdd(&sH[b], 1.f);
        }
    }
    __syncthreads();

    // wave 0: double prefix scan entirely in LDS/registers (no global chains)
    if (threadIdx.x < 64) {
        const int lane = threadIdx.x;
        float carry = 0.f, t0acc = 0.f;
        for (int ch = 0; ch < 32; ++ch) {
            const int b = ch * 64 + lane;
            const float cnt = sH[b];
            t0acc += (float)b * cnt;
            float ic = cnt;
#pragma unroll
            for (int off = 1; off < 64; off <<= 1) {
                const float t = __shfl_up(ic, off);
                if (lane >= off) ic += t;
            }
            sH[b] = carry + ic;             // inclusive prefix P (in place)
            carry += __shfl(ic, 63);
        }
        const float N = carry;
#pragma unroll
        for (int off = 32; off > 0; off >>= 1) t0acc += __shfl_down(t0acc, off);
        const float t0tot = __shfl(t0acc, 0);
        const float T0 = WB * (t0tot + 0.5f * N);

        float* T = tail + P_TTAB + (unsigned)blk * 2049u;
        float carryQ = 0.f;
        for (int ch = 0; ch < 32; ++ch) {
            const int b = ch * 64 + lane;
            const float pv = sH[b];
            float ic = pv;
#pragma unroll
            for (int off = 1; off < 64; off <<= 1) {
                const float t = __shfl_up(ic, off);
                if (lane >= off) ic += t;
            }
            const float Q = carryQ + ic - pv;   // exclusive prefix of P
            T[b] = T0 + WB * (2.f * Q - (float)b * N);
            carryQ += __shfl(ic, 63);
        }
        if (lane == 0) {
            T[NBUCK] = T0 + WB * (2.f * carryQ - (float)NBUCK * N);
            tail[P_STAB + blk] = T0 - 6.f * N;  // sum of snapped values
        }
    }
}

// ---------------------------------------------------------------------------
// 2) query: 147 blocks = (c, tap). Inclusion-exclusion:
//    abs = sum_16 T_part(k) - sum_6 T_row(k) - sum_6 T_col(k) + exact corners
//    lin = k*212992 - (sum S_part - sum S_row - sum S_col) + corner (k-v)
//    28 table lerps read directly from global on the 32 sl0-threads (one
//    independent-load burst); corners staged in LDS.
// ---------------------------------------------------------------------------
__global__ __launch_bounds__(256) void query_kernel(
    const float* __restrict__ Kh, const float* __restrict__ Km,
    const float* __restrict__ tail, float* __restrict__ gsum)
{
    __shared__ float sC[2304];
    __shared__ float sredA[32][8];
    __shared__ float sredL[32][8];

    const int c  = blockIdx.x / 49;
    const int t  = blockIdx.x - c * 49;
    const int dy = t / 7, dx = t - dy * 7;

    for (int i = threadIdx.x; i < 2304; i += 256) {
        const int cell = i >> 6, batch = i & 63;
        const int qr = cell / 6, qc = cell - qr * 6;
        const int ri = (qr < dy) ? qr : 6 + qr;
        const int ci = (qc < dx) ? qc : 6 + qc;
        sC[i] = tail[P_PACK + ((unsigned)c * 144 + ri * 12 + ci) * 64u + batch];
    }
    __syncthreads();

    const int q  = threadIdx.x >> 3;    // 0..31 = hm*16+o
    const int sl = threadIdx.x & 7;
    const int hm = q >> 4, o = q & 15;
    const float k = (hm ? Km : Kh)[o * 147 + c * 49 + t];

    float accA = 0.f, accL = 0.f;
    for (int step = 0; step < 288; ++step) {          // exact corners
        const float v = sC[sl + 8 * step];
        accA += fabsf(k - v);
        accL += k - v;
    }
    if (sl == 0) {
        const float u = fmaf(k, SCALE, 1024.f);
        const int j = min(max((int)u, 0), NBUCK - 1);
        const float fr = u - (float)j;
        float A = 0.f, Sm = 0.f;
#pragma unroll
        for (int s = 0; s < 28; ++s) {
            int slot; float sgn;
            if (s < 16)      { slot = s; sgn = 1.f; }
            else if (s < 22) { const int qq = s - 16; slot = 16 + ((qq < dy) ? qq : 6 + qq); sgn = -1.f; }
            else             { const int qq = s - 22; slot = 28 + ((qq < dx) ? qq : 6 + qq); sgn = -1.f; }
            const float* T = tail + P_TTAB + (unsigned)(c * 40 + slot) * 2049u;
            const float lerp = T[j] + fr * (T[j + 1] - T[j]);
            A  += sgn * lerp;
            Sm += sgn * tail[P_STAB + c * 40 + slot];
        }
        accA += A;
        accL += k * 212992.f - Sm;      // 212992 = (58*58 - 36) * 64
    }
    sredA[q][sl] = accA;
    sredL[q][sl] = accL;
    __syncthreads();
    if (threadIdx.x < 64) {
        const int idx  = threadIdx.x >> 1;
        const int part = threadIdx.x & 1;
        const float (*sr)[8] = part ? sredL : sredA;
        float s = 0.f;
#pragma unroll
        for (int qq = 0; qq < 8; ++qq) s += sr[idx][qq];
        atomicAdd(&gsum[part * 32 + idx], s);
    }
}

// ---------------------------------------------------------------------------
// 3) fill: fold A/L banks -> s_hit/s_miss; broadcast-fill 124 MB (roofline).
// ---------------------------------------------------------------------------
__global__ __launch_bounds__(256) void fill_kernel(
    const float* __restrict__ gsum, v4f* __restrict__ out, unsigned n4)
{
    __shared__ float sv[48];
    if (threadIdx.x < 48) {
        const int o = threadIdx.x & 15, grp = threadIdx.x >> 4;
        const float h = -0.5f * (gsum[32 + o] + gsum[o]);
        const float m =  0.5f * (gsum[16 + o] - gsum[48 + o]);
        sv[threadIdx.x] = (grp == 0) ? (h - m) : ((grp == 1) ? h : m);
    }
    __syncthreads();
    const unsigned stride = gridDim.x * blockDim.x;
    for (unsigned i = blockIdx.x * blockDim.x + threadIdx.x; i < n4; i += stride) {
        const unsigned f = i * 4u;
        const unsigned w   = f / OUT1;
        const unsigned rem = f - w * OUT1;
        const unsigned o   = (rem % OSEG) / SEG;
        const float val = sv[w * 16 + o];
        v4f pk = {val, val, val, val};
        __builtin_nontemporal_store(pk, &out[i]);
    }
}

extern "C" void kernel_launch(void* const* d_in, const int* in_sizes, int n_in,
                              void* d_out, int out_size, void* d_ws, size_t ws_size,
                              hipStream_t stream)
{
    const float* x  = (const float*)d_in[0];
    const float* Kh = (const float*)d_in[1];
    const float* Km = (const float*)d_in[2];
    float* out  = (float*)d_out;
    float* tail = out + TAIL_BASE;
    float* gsum = (float*)d_ws;    // 64 floats: [0..32) A-bank, [32..64) L-bank

    build_kernel<<<120, 1024, 0, stream>>>(x, tail, gsum);
    query_kernel<<<147, 256, 0, stream>>>(Kh, Km, tail, gsum);
    fill_kernel <<<4096, 256, 0, stream>>>(gsum, (v4f*)out, NOUT / 4u);
}